// Round 6
// baseline (566.016 us; speedup 1.0000x reference)
//
#include <hip/hip_runtime.h>
#include <math.h>

#define SPLIT 16
#define CER 64      // rows per ce block
#define CEC 81      // specialized class count
#define TKJ 16      // topk regs/thread (supports P <= 16384)

// ---------------- wave helpers (wave = 64 lanes) ----------------
__device__ __forceinline__ float wave_sum(float v) {
  for (int m = 32; m > 0; m >>= 1) v += __shfl_xor(v, m, 64);
  return v;
}
__device__ __forceinline__ int wave_sum_i(int v) {
  for (int m = 32; m > 0; m >>= 1) v += __shfl_xor(v, m, 64);
  return v;
}
__device__ __forceinline__ unsigned long long wave_max_key(unsigned long long k) {
  for (int m = 32; m > 0; m >>= 1) {
    unsigned lo = (unsigned)k, hi = (unsigned)(k >> 32);
    lo = __shfl_xor(lo, m, 64); hi = __shfl_xor(hi, m, 64);
    unsigned long long o = ((unsigned long long)hi << 32) | lo;
    if (o > k) k = o;
  }
  return k;
}

// ---------------- M1: per-prior best gt + per-gt best prior (atomicMax) ----
// grid = (SPLIT, B), block = 256. key = (iou_bits<<32)|(0x7FFFFFFF-p):
// iou>=0 so float bits are order-monotone; ties -> smaller p wins (first-max).
__global__ __launch_bounds__(256) void match1_kernel(
    const float* __restrict__ priors, const float* __restrict__ gt_box,
    float* __restrict__ best_iou, int* __restrict__ best_gt,
    unsigned long long* __restrict__ gt_best,   // [B,G], pre-zeroed
    int P, int G, int chunk)
{
  const int b = blockIdx.y;
  const int p0 = blockIdx.x * chunk;
  const int p1 = min(p0 + chunk, P);
  const int tid = threadIdx.x, lane = tid & 63;

  __shared__ float sgx1[64], sgy1[64], sgx2[64], sgy2[64], sga[64];
  for (int g = tid; g < G; g += 256) {
    float x1 = gt_box[((size_t)b * G + g) * 4 + 0];
    float y1 = gt_box[((size_t)b * G + g) * 4 + 1];
    float x2 = gt_box[((size_t)b * G + g) * 4 + 2];
    float y2 = gt_box[((size_t)b * G + g) * 4 + 3];
    sgx1[g] = x1; sgy1[g] = y1; sgx2[g] = x2; sgy2[g] = y2;
    sga[g] = (x2 - x1) * (y2 - y1);
  }
  __syncthreads();

  for (int g0 = 0; g0 < G; g0 += 16) {
    const int gc = min(16, G - g0);
    unsigned long long bkey[16];
#pragma unroll
    for (int gg = 0; gg < 16; ++gg) bkey[gg] = 0ull;

    for (int p = p0 + tid; p < p1; p += 256) {
      const size_t ip = (size_t)b * P + p;
      float pcx = priors[p * 4 + 0], pcy = priors[p * 4 + 1];
      float pw = priors[p * 4 + 2], ph = priors[p * 4 + 3];
      float px1 = pcx - pw * 0.5f, py1 = pcy - ph * 0.5f;
      float px2 = pcx + pw * 0.5f, py2 = pcy + ph * 0.5f;
      float pa = (px2 - px1) * (py2 - py1);
      float bv; int bg;
      if (g0 == 0) { bv = -INFINITY; bg = 0; }
      else { bv = best_iou[ip]; bg = best_gt[ip]; }   // carry across chunks
#pragma unroll
      for (int gg = 0; gg < 16; ++gg) {
        if (gg < gc) {
          int g = g0 + gg;
          float ix = fmaxf(fminf(sgx2[g], px2) - fmaxf(sgx1[g], px1), 0.f);
          float iy = fmaxf(fminf(sgy2[g], py2) - fmaxf(sgy1[g], py1), 0.f);
          float inter = ix * iy;
          float ov = inter / (sga[g] + pa - inter);
          if (ov > bv) { bv = ov; bg = g; }           // g ascending: first-max
          unsigned long long key =
              ((unsigned long long)__float_as_uint(ov) << 32) |
              (unsigned)(0x7FFFFFFF - p);
          if (key > bkey[gg]) bkey[gg] = key;
        }
      }
      best_iou[ip] = bv;
      best_gt[ip] = bg;
    }

#pragma unroll
    for (int gg = 0; gg < 16; ++gg) {
      if (gg < gc) {
        unsigned long long k = wave_max_key(bkey[gg]);
        if (lane == 0 && k)
          atomicMax(&gt_best[(size_t)b * G + g0 + gg], k);
      }
    }
  }
}

// ---------------- K2: fused CE + matching epilogue (C == 81) --------------
// grid = (ceil(P/CER), B), block = 256: 64 rows/block, 4 threads/row.
// LDS ~22.8KB -> 7 blocks/CU (28 waves). Row reduce: strided c=q+4i reads
// (bank word = 17r+q+4i mod 32: only 2-way aliasing = free) + 2 shfl_xor.
// Computes class_t inline (incl. forced priors decoded from gt_best),
// CE -> loss_gt (pos rows 0), pos-CE / loc smooth-L1 / num_pos accumulators.
__global__ __launch_bounds__(256) void ce81_kernel(
    const float* __restrict__ class_p, const float* __restrict__ priors,
    const float* __restrict__ gt_box, const int* __restrict__ gt_class,
    const float* __restrict__ loc_p,
    const float* __restrict__ best_iou, const int* __restrict__ best_gt,
    const unsigned long long* __restrict__ gt_best,
    float* __restrict__ loss_gt, int* __restrict__ num_pos_arr,
    float* __restrict__ lla, float* __restrict__ lca, int* __restrict__ ntot,
    int P, int G)
{
  __shared__ float srow[CER * CEC];      // 20736 B
  __shared__ float4 sgb[64];
  __shared__ int sgtc[64], sforce[64];
  __shared__ float sbi[CER];
  __shared__ int sbg[CER];
  __shared__ float sr_pc[4], sr_ls[4];
  __shared__ int sr_cnt[4];

  const int b = blockIdx.y;
  const int p0 = blockIdx.x * CER;
  const int rows = min(CER, P - p0);
  const int tid = threadIdx.x;

  // stage class rows (coalesced float4; block base is 16B-aligned when
  // (b*P+p0)*CEC*4 % 16 == 0 — guard for generality)
  const float* gsrc = class_p + ((size_t)b * P + p0) * CEC;
  const int nf = rows * CEC;
  if ((((unsigned long long)(uintptr_t)gsrc) & 15ull) == 0) {
    const int n4 = nf >> 2;
    for (int i = tid; i < n4; i += 256)
      ((float4*)srow)[i] = ((const float4*)gsrc)[i];
    for (int i = (n4 << 2) + tid; i < nf; i += 256) srow[i] = gsrc[i];
  } else {
    for (int i = tid; i < nf; i += 256) srow[i] = gsrc[i];
  }
  // stage per-row match results
  for (int i = tid; i < rows; i += 256) {
    sbi[i] = best_iou[(size_t)b * P + p0 + i];
    sbg[i] = best_gt[(size_t)b * P + p0 + i];
  }
  // stage gt data + decode forced priors
  if (tid < G) {
    sgb[tid] = ((const float4*)gt_box)[(size_t)b * G + tid];
    sgtc[tid] = gt_class[(size_t)b * G + tid];
    unsigned long long k = gt_best[(size_t)b * G + tid];
    sforce[tid] = 0x7FFFFFFF - (int)(unsigned)(k & 0xFFFFFFFFu);
  }
  __syncthreads();

  const int r = tid >> 2, q = tid & 3;
  const int lane = tid & 63, wv = tid >> 6;
  float posce = 0.f, lsum = 0.f; int cnt = 0;

  if (r < rows) {
    const float* x = srow + r * CEC;
    float m = -INFINITY;
    for (int c = q; c < CEC; c += 4) m = fmaxf(m, x[c]);
    m = fmaxf(m, __shfl_xor(m, 1, 64));
    m = fmaxf(m, __shfl_xor(m, 2, 64));
    float s = 0.f;
    for (int c = q; c < CEC; c += 4) s += __expf(x[c] - m);
    s += __shfl_xor(s, 1, 64);
    s += __shfl_xor(s, 2, 64);

    if (q == 0) {
      const int p = p0 + r;
      const size_t row = (size_t)b * P + p;
      const float bi = sbi[r];
      const int bg = sbg[r];
      bool forced = false;
      for (int g = 0; g < G; ++g) forced |= (p == sforce[g]);
      const bool pos = forced || (bi >= 0.5f);
      const int ct = pos ? (sgtc[bg] + 1) : 0;
      const float ce = m + __logf(s) - x[ct];
      float lg;
      if (pos) {
        lg = 0.f; posce = ce; cnt = 1;
        // localization smooth-L1 vs encode(gt, prior)
        float pcx = priors[p * 4 + 0], pcy = priors[p * 4 + 1];
        float pw = priors[p * 4 + 2], ph = priors[p * 4 + 3];
        float4 gb = sgb[bg];
        float tx = ((gb.x + gb.z) * 0.5f - pcx) / (pw * 0.1f);
        float ty = ((gb.y + gb.w) * 0.5f - pcy) / (ph * 0.1f);
        float tw = logf((gb.z - gb.x) / pw) / 0.2f;
        float th = logf((gb.w - gb.y) / ph) / 0.2f;
        const float* lp = loc_p + row * 4;
        float t0[4] = {tx, ty, tw, th};
#pragma unroll
        for (int j = 0; j < 4; ++j) {
          float d = fabsf(lp[j] - t0[j]);
          lsum += (d < 1.f) ? 0.5f * d * d : d - 0.5f;
        }
      } else {
        lg = fmaxf(ce, 0.f);    // clamp keeps uint-compare monotone in topk
      }
      loss_gt[row] = lg;
    }
  }

  posce = wave_sum(posce);
  lsum = wave_sum(lsum);
  cnt = wave_sum_i(cnt);
  if (lane == 0) { sr_pc[wv] = posce; sr_ls[wv] = lsum; sr_cnt[wv] = cnt; }
  __syncthreads();
  if (tid == 0) {
    float pc = sr_pc[0] + sr_pc[1] + sr_pc[2] + sr_pc[3];
    float ls = sr_ls[0] + sr_ls[1] + sr_ls[2] + sr_ls[3];
    int c = sr_cnt[0] + sr_cnt[1] + sr_cnt[2] + sr_cnt[3];
    if (c) { atomicAdd(&num_pos_arr[b], c); atomicAdd(ntot, c); }
    if (ls != 0.f) atomicAdd(lla, ls);
    if (pc != 0.f) atomicAdd(lca, pc);
  }
}

// ---------------- generic-C fallback (correct for any C; unused at C=81) ---
__global__ void ce_generic_kernel(
    const float* __restrict__ class_p, const float* __restrict__ priors,
    const float* __restrict__ gt_box, const int* __restrict__ gt_class,
    const float* __restrict__ loc_p,
    const float* __restrict__ best_iou, const int* __restrict__ best_gt,
    const unsigned long long* __restrict__ gt_best,
    float* __restrict__ loss_gt, int* __restrict__ num_pos_arr,
    float* __restrict__ lla, float* __restrict__ lca, int* __restrict__ ntot,
    int P, int G, int C)
{
  __shared__ float4 sgb[64];
  __shared__ int sgtc[64], sforce[64];
  __shared__ float sr_pc[4], sr_ls[4];
  __shared__ int sr_cnt[4];
  const int b = blockIdx.y;
  const int p = blockIdx.x * 256 + threadIdx.x;
  const int tid = threadIdx.x, lane = tid & 63, wv = tid >> 6;
  if (tid < G) {
    sgb[tid] = ((const float4*)gt_box)[(size_t)b * G + tid];
    sgtc[tid] = gt_class[(size_t)b * G + tid];
    unsigned long long k = gt_best[(size_t)b * G + tid];
    sforce[tid] = 0x7FFFFFFF - (int)(unsigned)(k & 0xFFFFFFFFu);
  }
  __syncthreads();
  float posce = 0.f, lsum = 0.f; int cnt = 0;
  if (p < P) {
    const size_t row = (size_t)b * P + p;
    const float* x = class_p + row * C;
    float m = -INFINITY;
    for (int c = 0; c < C; ++c) m = fmaxf(m, x[c]);
    float s = 0.f;
    for (int c = 0; c < C; ++c) s += __expf(x[c] - m);
    const float bi = best_iou[row];
    const int bg = best_gt[row];
    bool forced = false;
    for (int g = 0; g < G; ++g) forced |= (p == sforce[g]);
    const bool pos = forced || (bi >= 0.5f);
    const int ct = pos ? (sgtc[bg] + 1) : 0;
    const float ce = m + __logf(s) - x[ct];
    float lg;
    if (pos) {
      lg = 0.f; posce = ce; cnt = 1;
      float pcx = priors[p * 4 + 0], pcy = priors[p * 4 + 1];
      float pw = priors[p * 4 + 2], ph = priors[p * 4 + 3];
      float4 gb = sgb[bg];
      float t0[4] = {((gb.x + gb.z) * 0.5f - pcx) / (pw * 0.1f),
                     ((gb.y + gb.w) * 0.5f - pcy) / (ph * 0.1f),
                     logf((gb.z - gb.x) / pw) / 0.2f,
                     logf((gb.w - gb.y) / ph) / 0.2f};
      const float* lp = loc_p + row * 4;
#pragma unroll
      for (int j = 0; j < 4; ++j) {
        float d = fabsf(lp[j] - t0[j]);
        lsum += (d < 1.f) ? 0.5f * d * d : d - 0.5f;
      }
    } else lg = fmaxf(ce, 0.f);
    loss_gt[row] = lg;
  }
  posce = wave_sum(posce); lsum = wave_sum(lsum); cnt = wave_sum_i(cnt);
  if (lane == 0) { sr_pc[wv] = posce; sr_ls[wv] = lsum; sr_cnt[wv] = cnt; }
  __syncthreads();
  if (tid == 0) {
    float pc = sr_pc[0] + sr_pc[1] + sr_pc[2] + sr_pc[3];
    float ls = sr_ls[0] + sr_ls[1] + sr_ls[2] + sr_ls[3];
    int c = sr_cnt[0] + sr_cnt[1] + sr_cnt[2] + sr_cnt[3];
    if (c) { atomicAdd(&num_pos_arr[b], c); atomicAdd(ntot, c); }
    if (ls != 0.f) atomicAdd(lla, ls);
    if (pc != 0.f) atomicAdd(lca, pc);
  }
}

// ---------------- K3: per-batch sum of top-k + last-block finalize --------
// grid = B, block = 1024. Values in registers; 31-bit binary search on float
// bit pattern. sum(top-k) = sum(v > v_k) + v_k * (k - count(> v_k)).
__global__ __launch_bounds__(1024) void topk_fin_kernel(
    const float* __restrict__ loss_gt, const int* __restrict__ num_pos_arr,
    float* __restrict__ lla, float* __restrict__ lca, int* __restrict__ ntot,
    int* __restrict__ done, float* __restrict__ out,
    int P, int negpos_ratio, int B)
{
  __shared__ int scnt[16];
  __shared__ float ssum[16];
  const int b = blockIdx.x;
  const int tid = threadIdx.x, lane = tid & 63, wv = tid >> 6;
  const int np = num_pos_arr[b];
  const int k = min(negpos_ratio * np, P - 1);

  if (k > 0) {
    unsigned uv[TKJ];
#pragma unroll
    for (int j = 0; j < TKJ; ++j) {
      int i = tid + j * 1024;
      uv[j] = (i < P) ? __float_as_uint(loss_gt[(size_t)b * P + i]) : 0u;
    }
    unsigned u = 0;
    for (int bit = 30; bit >= 0; --bit) {
      unsigned cand = u | (1u << bit);
      int cnt = 0;
#pragma unroll
      for (int j = 0; j < TKJ; ++j) cnt += (uv[j] >= cand) ? 1 : 0;
      cnt = wave_sum_i(cnt);
      if (lane == 0) scnt[wv] = cnt;
      __syncthreads();
      int tot = 0;
#pragma unroll
      for (int j = 0; j < 16; ++j) tot += scnt[j];
      if (tot >= k) u = cand;
      __syncthreads();
    }
    const float vk = __uint_as_float(u);
    int cgt = 0; float sgt = 0.f;
#pragma unroll
    for (int j = 0; j < TKJ; ++j)
      if (uv[j] > u) { cgt++; sgt += __uint_as_float(uv[j]); }
    cgt = wave_sum_i(cgt); sgt = wave_sum(sgt);
    if (lane == 0) { scnt[wv] = cgt; ssum[wv] = sgt; }
    __syncthreads();
    if (tid == 0) {
      int cg = 0; float sg = 0.f;
#pragma unroll
      for (int j = 0; j < 16; ++j) { cg += scnt[j]; sg += ssum[j]; }
      atomicAdd(lca, sg + vk * (float)(k - cg));
    }
  }

  // last block finalizes (atomic reads: coherent across XCDs)
  if (tid == 0) {
    __threadfence();
    int old = atomicAdd(done, 1);
    if (old == B - 1) {
      float N = (float)atomicAdd(ntot, 0);
      float L = atomicAdd(lla, 0.f);
      float Cc = atomicAdd(lca, 0.f);
      out[0] = L / N;
      out[1] = Cc / N;
    }
  }
}

extern "C" void kernel_launch(void* const* d_in, const int* in_sizes, int n_in,
                              void* d_out, int out_size, void* d_ws, size_t ws_size,
                              hipStream_t stream) {
  const float* loc_p   = (const float*)d_in[0];
  const float* class_p = (const float*)d_in[1];
  const float* priors  = (const float*)d_in[2];
  const float* gt_box  = (const float*)d_in[3];
  const int*   gt_cls  = (const int*)d_in[4];

  const int P = in_sizes[2] / 4;
  const int B = in_sizes[0] / (4 * P);
  const int C = (int)((long long)in_sizes[1] / ((long long)B * P));
  const int G = in_sizes[4] / B;
  const long long BP = (long long)B * P;

  char* w = (char*)d_ws;
  float* best_iou = (float*)w; w += BP * 4;
  int*   bst_gt   = (int*)w;   w += BP * 4;
  float* loss_gt  = (float*)w; w += BP * 4;
  char* zbase = w;                     // ---- zero-initialized region ----
  float* lla  = (float*)w; w += 4;
  float* lca  = (float*)w; w += 4;
  int*   ntot = (int*)w;   w += 4;
  int*   done = (int*)w;   w += 4;     // gt_best now 8-aligned (16B offset)
  unsigned long long* gt_best = (unsigned long long*)w; w += (size_t)B * G * 8;
  int* num_pos = (int*)w;  w += (size_t)B * 4;
  const size_t zbytes = (size_t)(w - zbase);

  hipMemsetAsync(zbase, 0, zbytes, stream);

  const int chunk = (P + SPLIT - 1) / SPLIT;
  match1_kernel<<<dim3(SPLIT, B), 256, 0, stream>>>(
      priors, gt_box, best_iou, bst_gt, gt_best, P, G, chunk);

  if (C == CEC) {
    ce81_kernel<<<dim3((P + CER - 1) / CER, B), 256, 0, stream>>>(
        class_p, priors, gt_box, gt_cls, loc_p, best_iou, bst_gt, gt_best,
        loss_gt, num_pos, lla, lca, ntot, P, G);
  } else {
    ce_generic_kernel<<<dim3((P + 255) / 256, B), 256, 0, stream>>>(
        class_p, priors, gt_box, gt_cls, loc_p, best_iou, bst_gt, gt_best,
        loss_gt, num_pos, lla, lca, ntot, P, G, C);
  }

  topk_fin_kernel<<<B, 1024, 0, stream>>>(
      loss_gt, num_pos, lla, lca, ntot, done, (float*)d_out, P, 3, B);
}